// Round 3
// baseline (4329.545 us; speedup 1.0000x reference)
//
#include <hip/hip_runtime.h>

typedef short bf16x8 __attribute__((ext_vector_type(8)));
typedef float f32x4 __attribute__((ext_vector_type(4)));

#define DEV __device__ __forceinline__

DEV short f2bf(float f) {
  union { float f; unsigned u; } v; v.f = f;
  unsigned r = v.u + 0x7FFFu + ((v.u >> 16) & 1u);
  return (short)(r >> 16);
}
DEV float bf2f(short s) {
  union { unsigned u; float f; } v; v.u = ((unsigned)(unsigned short)s) << 16;
  return v.f;
}
DEV float sigm(float x) { return 1.0f / (1.0f + __expf(-x)); }
DEV float tanh_(float x) {
  float a = fabsf(x);
  float e = __expf(-2.0f * a);
  float t = (1.0f - e) / (1.0f + e);
  return copysignf(t, x);
}

// ---------------- LDS layout (bytes), 32 batch rows per wg.
// bf16 2D arrays XOR-swizzled: byte ^= (row&7)<<4
#define LDS_S    0        // s  : 32 x 128 bf16, stride 256   (8 KB)
#define LDS_H0   8192     // h0 : 32 x 256 bf16, stride 512   (16 KB)
#define LDS_H1   24576    // h1 : 32 x 256 bf16, stride 512   (16 KB)
#define LDS_U    40960    // u  : 32 x 256 bf16, stride 512   (16 KB)
#define LDS_NX   40960    // nx : 32 x 512 bf16, stride 1024  (32 KB, overlaps U)
#define LDS_PROB 73728    // 8 x 32 f32 (1 KB)
#define LDS_CF   8192     // init staging: 32 x 512 bf16, stride 1024 (overlaps H0+H1)
#define LDS_SZ   74752

// ---------------- workspace offsets (shorts)
#define OFF_SE1 0
#define OFF_SE2 131072
#define OFF_W0  163840
#define OFF_W1  557056
#define OFF_OM1 1081344
#define OFF_OM2 1179648
#define OFF_PE1 1310720

// Weight prep: gather into MFMA fragment order.
__global__ void prep_frag(const float* __restrict__ srcA, const float* __restrict__ srcB,
                          short* __restrict__ dst, int N, int K, int ksplit)
{
  const int e = blockIdx.x * 256 + threadIdx.x;
  if (e >= N * K) return;
  const int f = e >> 9;
  const int rix = e & 511;
  const int lane = rix >> 3, j = rix & 7;
  const int KK = K >> 5;
  const int ntile = f / KK, kk = f - ntile * KK;
  const int n = ntile * 16 + (lane & 15);
  const int k = kk * 32 + ((lane >> 4) << 3) + j;
  float v;
  if (k < ksplit) v = srcA[(size_t)n * ksplit + k];
  else            v = srcB[(size_t)n * (K - ksplit) + (k - ksplit)];
  dst[e] = f2bf(v);
}

template<int NT, int MT>
DEV void zacc(f32x4 (&acc)[NT][MT]) {
  #pragma unroll
  for (int n = 0; n < NT; ++n)
    #pragma unroll
    for (int m = 0; m < MT; ++m)
      acc[n][m] = (f32x4){0.f, 0.f, 0.f, 0.f};
}

// Tile-matmul with double-buffered B (weight) prefetch. MT=2 => 32 rows.
template<int KK, int NT, int MT>
DEV void mm_tiles(const char* sm, int aBase0, int aStride0, int splitKB,
                  int aBase1, int aStride1,
                  const short* __restrict__ wf, int ntBase, int ntStride,
                  f32x4 (&acc)[NT][MT], int lane)
{
  const int l15 = lane & 15, l4 = lane >> 4;
  const short* wp = wf + lane * 8;
  bf16x8 b[2][NT];
  #pragma unroll
  for (int nt = 0; nt < NT; ++nt)
    b[0][nt] = *(const bf16x8*)(wp + (size_t)((ntBase + nt * ntStride) * KK) * 512);
  #pragma unroll
  for (int kk = 0; kk < KK; ++kk) {
    const int cb = kk & 1, nb = cb ^ 1;
    if (kk + 1 < KK) {
      #pragma unroll
      for (int nt = 0; nt < NT; ++nt)
        b[nb][nt] = *(const bf16x8*)(wp + (size_t)((ntBase + nt * ntStride) * KK + kk + 1) * 512);
    }
    const int kb = kk * 64 + l4 * 16;
    bf16x8 a[MT];
    #pragma unroll
    for (int m = 0; m < MT; ++m) {
      const int r = m * 16 + l15;
      int off;
      if (kb < splitKB) off = aBase0 + r * aStride0 + (kb ^ ((r & 7) << 4));
      else              off = aBase1 + r * aStride1 + ((kb - splitKB) ^ ((r & 7) << 4));
      a[m] = *(const bf16x8*)(sm + off);
    }
    #pragma unroll
    for (int nt = 0; nt < NT; ++nt)
      #pragma unroll
      for (int m = 0; m < MT; ++m)
        acc[nt][m] = __builtin_amdgcn_mfma_f32_16x16x32_bf16(a[m], b[cb][nt], acc[nt][m], 0, 0, 0);
  }
}

// LSTM elementwise for MT=2; c packed as 2xbf16 per reg (4 words), h likewise.
DEV void lstm_ew2(f32x4 (&acc)[4][2], f32x4 bv, unsigned (&cpk)[4], unsigned (&hp)[4])
{
  #pragma unroll
  for (int m = 0; m < 2; ++m)
    #pragma unroll
    for (int qh = 0; qh < 2; ++qh) {
      const int pi = m * 2 + qh;
      const unsigned oldc = cpk[pi];
      unsigned newc = 0, newh = 0;
      #pragma unroll
      for (int ql = 0; ql < 2; ++ql) {
        const int q = qh * 2 + ql;
        const float gi = acc[0][m][q] + bv[0];
        const float gf = acc[1][m][q] + bv[1];
        const float gg = acc[2][m][q] + bv[2];
        const float go = acc[3][m][q] + bv[3];
        const float cold = bf2f((short)((oldc >> (ql * 16)) & 0xFFFFu));
        const float c = sigm(gf) * cold + sigm(gi) * tanh_(gg);
        const float h = sigm(go) * tanh_(c);
        newc |= ((unsigned)(unsigned short)f2bf(c)) << (ql * 16);
        newh |= ((unsigned)(unsigned short)f2bf(h)) << (ql * 16);
      }
      cpk[pi] = newc;
      hp[pi] = newh;
    }
}

// ---------------- main fused kernel: 32 batch rows per workgroup, full scan + PE head
__global__ __launch_bounds__(512, 2) void atg_main(
    const float* __restrict__ base, const float* __restrict__ cf,
    const float* __restrict__ b_se1, const float* __restrict__ b_se2,
    const float* __restrict__ b_ih0, const float* __restrict__ b_hh0,
    const float* __restrict__ b_ih1, const float* __restrict__ b_hh1,
    const float* __restrict__ b_om1, const float* __restrict__ b_om2,
    const float* __restrict__ b_pe1, const float* __restrict__ w_pe2,
    const float* __restrict__ b_pe2,
    const short* __restrict__ wsb,
    float* __restrict__ outStates, float* __restrict__ probs,
    float* __restrict__ outS, float* __restrict__ outFinal, int nsteps)
{
  __shared__ __align__(16) char sm[LDS_SZ];
  const int tid = threadIdx.x;
  const int lane = tid & 63, wid = tid >> 6;
  const int l15 = lane & 15, l4 = lane >> 4;
  const int row0 = blockIdx.x * 32;

  // cur in registers: curv[i*8+m*4+q] = cur[m*16+l4*4+q][(wid*4+i)*16+l15]
  float curv[32];
  #pragma unroll
  for (int i = 0; i < 4; ++i)
    #pragma unroll
    for (int m = 0; m < 2; ++m)
      #pragma unroll
      for (int q = 0; q < 4; ++q)
        curv[i * 8 + m * 4 + q] =
            base[(size_t)(row0 + m * 16 + l4 * 4 + q) * 512 + (wid * 4 + i) * 16 + l15];

  // ---- stage counterfactual_scenario -> LDS_CF (bf16, swizzled)
  {
    const int r = tid >> 4, ci = tid & 15;
    const float* src = cf + (size_t)(row0 + r) * 512;
    #pragma unroll
    for (int i = 0; i < 8; ++i) {
      const int c = ci * 4 + i * 64;
      const float4 v = *(const float4*)(src + c);
      short4 h; h.x = f2bf(v.x); h.y = f2bf(v.y); h.z = f2bf(v.z); h.w = f2bf(v.w);
      *(short4*)(sm + LDS_CF + r * 1024 + ((c * 2) ^ ((r & 7) << 4))) = h;
    }
  }
  __syncthreads();

  // ---- se1: relu(cf @ Wse1^T + b_se1) -> U
  {
    f32x4 acc[2][2]; zacc(acc);
    mm_tiles<16, 2, 2>(sm, LDS_CF, 1024, 1 << 28, LDS_CF, 1024, wsb + OFF_SE1, wid * 2, 1, acc, lane);
    #pragma unroll
    for (int nt = 0; nt < 2; ++nt) {
      const int cc = (wid * 2 + nt) * 16 + l15;
      const float bv = b_se1[cc];
      #pragma unroll
      for (int m = 0; m < 2; ++m)
        #pragma unroll
        for (int q = 0; q < 4; ++q) {
          const int rr = m * 16 + l4 * 4 + q;
          const float u = fmaxf(acc[nt][m][q] + bv, 0.0f);
          *(short*)(sm + LDS_U + rr * 512 + ((cc * 2) ^ ((rr & 7) << 4))) = f2bf(u);
        }
    }
  }
  __syncthreads();

  // ---- se2: u @ Wse2^T + b_se2 -> S (bf16) + outS (f32); zero h0/h1 (overwrites CF)
  {
    f32x4 acc[1][2]; zacc(acc);
    mm_tiles<8, 1, 2>(sm, LDS_U, 512, 1 << 28, LDS_U, 512, wsb + OFF_SE2, wid, 1, acc, lane);
    const int cc = wid * 16 + l15;
    const float bv = b_se2[cc];
    #pragma unroll
    for (int m = 0; m < 2; ++m)
      #pragma unroll
      for (int q = 0; q < 4; ++q) {
        const int rr = m * 16 + l4 * 4 + q;
        const float v = acc[0][m][q] + bv;
        __builtin_nontemporal_store(v, outS + (size_t)(row0 + rr) * 128 + cc);
        *(short*)(sm + LDS_S + rr * 256 + ((cc * 2) ^ ((rr & 7) << 4))) = f2bf(v);
      }
    #pragma unroll
    for (int i = 0; i < 4; ++i)
      *(f32x4*)(sm + LDS_H0 + tid * 64 + i * 16) = (f32x4){0.f, 0.f, 0.f, 0.f};
  }
  __syncthreads();

  // ---- persistent LSTM biases (16 VGPR)
  f32x4 b0v[2], b1v[2];
  #pragma unroll
  for (int js = 0; js < 2; ++js) {
    f32x4 t0, t1;
    #pragma unroll
    for (int g = 0; g < 4; ++g) {
      const int c = g * 256 + (wid * 2 + js) * 16 + l15;
      t0[g] = b_ih0[c] + b_hh0[c];
      t1[g] = b_ih1[c] + b_hh1[c];
    }
    b0v[js] = t0; b1v[js] = t1;
  }

  unsigned c0[8], c1[8];
  #pragma unroll
  for (int i = 0; i < 8; ++i) { c0[i] = 0u; c1[i] = 0u; }

  for (int step = 0; step < nsteps; ++step) {
    unsigned hp[2][4];
    // ===== phase A: LSTM layer 0, A = [s | h0], K=384
    #pragma unroll
    for (int js = 0; js < 2; ++js) {
      f32x4 acc[4][2]; zacc(acc);
      mm_tiles<12, 4, 2>(sm, LDS_S, 256, 256, LDS_H0, 512, wsb + OFF_W0, wid * 2 + js, 16, acc, lane);
      lstm_ew2(acc, b0v[js], *(unsigned(*)[4])&c0[js * 4], hp[js]);
    }
    __syncthreads();                               // (1) old-h0 reads done
    #pragma unroll
    for (int js = 0; js < 2; ++js)
      #pragma unroll
      for (int m = 0; m < 2; ++m)
        #pragma unroll
        for (int q = 0; q < 4; ++q) {
          const int rr = m * 16 + l4 * 4 + q;
          const int cc = (wid * 2 + js) * 16 + l15;
          const unsigned v = hp[js][m * 2 + (q >> 1)] >> ((q & 1) * 16);
          *(short*)(sm + LDS_H0 + rr * 512 + ((cc * 2) ^ ((rr & 7) << 4))) = (short)v;
        }
    __syncthreads();                               // (2)
    // ===== phase B: LSTM layer 1, A = [h0 | h1], K=512
    #pragma unroll
    for (int js = 0; js < 2; ++js) {
      f32x4 acc[4][2]; zacc(acc);
      mm_tiles<16, 4, 2>(sm, LDS_H0, 512, 512, LDS_H1, 512, wsb + OFF_W1, wid * 2 + js, 16, acc, lane);
      lstm_ew2(acc, b1v[js], *(unsigned(*)[4])&c1[js * 4], hp[js]);
    }
    __syncthreads();                               // (3) old-h1 reads done
    #pragma unroll
    for (int js = 0; js < 2; ++js)
      #pragma unroll
      for (int m = 0; m < 2; ++m)
        #pragma unroll
        for (int q = 0; q < 4; ++q) {
          const int rr = m * 16 + l4 * 4 + q;
          const int cc = (wid * 2 + js) * 16 + l15;
          const unsigned v = hp[js][m * 2 + (q >> 1)] >> ((q & 1) * 16);
          *(short*)(sm + LDS_H1 + rr * 512 + ((cc * 2) ^ ((rr & 7) << 4))) = (short)v;
        }
    __syncthreads();                               // (4)
    // ===== phase C: u = relu([h1|s] @ Wom1^T + b_om1) -> U
    {
      f32x4 acc[2][2]; zacc(acc);
      mm_tiles<12, 2, 2>(sm, LDS_H1, 512, 512, LDS_S, 256, wsb + OFF_OM1, wid * 2, 1, acc, lane);
      #pragma unroll
      for (int nt = 0; nt < 2; ++nt) {
        const int cc = (wid * 2 + nt) * 16 + l15;
        const float bo1 = b_om1[cc];
        #pragma unroll
        for (int m = 0; m < 2; ++m)
          #pragma unroll
          for (int q = 0; q < 4; ++q) {
            const int rr = m * 16 + l4 * 4 + q;
            const float u = fmaxf(acc[nt][m][q] + bo1, 0.0f);
            *(short*)(sm + LDS_U + rr * 512 + ((cc * 2) ^ ((rr & 7) << 4))) = f2bf(u);
          }
      }
    }
    __syncthreads();                               // (5)
    // ===== phase D: nxt = cur + 0.1*tanh(u @ Wom2^T + b_om2); cur in regs
    {
      f32x4 acc[4][2]; zacc(acc);
      mm_tiles<8, 4, 2>(sm, LDS_U, 512, 1 << 28, LDS_U, 512, wsb + OFF_OM2, wid * 4, 1, acc, lane);
      #pragma unroll
      for (int i = 0; i < 4; ++i) {
        const int cc = (wid * 4 + i) * 16 + l15;
        const float bo2 = b_om2[cc];
        #pragma unroll
        for (int m = 0; m < 2; ++m)
          #pragma unroll
          for (int q = 0; q < 4; ++q) {
            const int rr = m * 16 + l4 * 4 + q;
            const int ci = i * 8 + m * 4 + q;
            const float nx = curv[ci] + 0.1f * tanh_(acc[i][m][q] + bo2);
            curv[ci] = nx;
            __builtin_nontemporal_store(nx,
                outStates + ((size_t)(row0 + rr) * nsteps + step) * 512 + cc);
          }
      }
    }
    __syncthreads();                               // (6) all U reads done (NX overlaps U)
    #pragma unroll
    for (int i = 0; i < 4; ++i)
      #pragma unroll
      for (int m = 0; m < 2; ++m)
        #pragma unroll
        for (int q = 0; q < 4; ++q) {
          const int rr = m * 16 + l4 * 4 + q;
          const int cc = (wid * 4 + i) * 16 + l15;
          *(short*)(sm + LDS_NX + rr * 1024 + ((cc * 2) ^ ((rr & 7) << 4))) =
              f2bf(curv[i * 8 + m * 4 + q]);
        }
    __syncthreads();                               // (7)
    // ===== phase PE: prob = sigmoid(relu(nx @ Wpe1^T + b_pe1) @ w_pe2 + b_pe2)
    {
      const int cc = wid * 16 + l15;
      const float bp1 = b_pe1[cc];
      const float w2v = w_pe2[cc];
      f32x4 acc[1][2]; zacc(acc);
      mm_tiles<16, 1, 2>(sm, LDS_NX, 1024, 1 << 28, LDS_NX, 1024, wsb + OFF_PE1, wid, 1, acc, lane);
      float part[8];
      #pragma unroll
      for (int m = 0; m < 2; ++m)
        #pragma unroll
        for (int q = 0; q < 4; ++q)
          part[m * 4 + q] = fmaxf(acc[0][m][q] + bp1, 0.0f) * w2v;
      #pragma unroll
      for (int d = 1; d < 16; d <<= 1)
        #pragma unroll
        for (int i = 0; i < 8; ++i)
          part[i] += __shfl_xor(part[i], d);
      if (l15 == 0) {
        #pragma unroll
        for (int m = 0; m < 2; ++m)
          #pragma unroll
          for (int q = 0; q < 4; ++q)
            *(float*)(sm + LDS_PROB + (wid * 32 + m * 16 + l4 * 4 + q) * 4) = part[m * 4 + q];
      }
    }
    __syncthreads();                               // (8)
    if (tid < 32) {
      float ssum = b_pe2[0];
      #pragma unroll
      for (int w = 0; w < 8; ++w)
        ssum += *(const float*)(sm + LDS_PROB + (w * 32 + tid) * 4);
      const float p = 1.0f / (1.0f + __expf(-ssum));
      __builtin_nontemporal_store(p, probs + (size_t)(row0 + tid) * nsteps + step);
    }
    // no barrier: next write to PROB/NX is ≥2 barriers away
  }

  // ---- final timeline state
  #pragma unroll
  for (int i = 0; i < 4; ++i)
    #pragma unroll
    for (int m = 0; m < 2; ++m)
      #pragma unroll
      for (int q = 0; q < 4; ++q)
        __builtin_nontemporal_store(curv[i * 8 + m * 4 + q],
            outFinal + (size_t)(row0 + m * 16 + l4 * 4 + q) * 512 + (wid * 4 + i) * 16 + l15);
}

extern "C" void kernel_launch(void* const* d_in, const int* in_sizes, int n_in,
                              void* d_out, int out_size, void* d_ws, size_t ws_size,
                              hipStream_t stream)
{
  const float* base  = (const float*)d_in[0];
  const float* cf    = (const float*)d_in[1];
  const float* w_se1 = (const float*)d_in[2];
  const float* b_se1 = (const float*)d_in[3];
  const float* w_se2 = (const float*)d_in[4];
  const float* b_se2 = (const float*)d_in[5];
  const float* w_ih0 = (const float*)d_in[6];
  const float* w_hh0 = (const float*)d_in[7];
  const float* b_ih0 = (const float*)d_in[8];
  const float* b_hh0 = (const float*)d_in[9];
  const float* w_ih1 = (const float*)d_in[10];
  const float* w_hh1 = (const float*)d_in[11];
  const float* b_ih1 = (const float*)d_in[12];
  const float* b_hh1 = (const float*)d_in[13];
  const float* w_om1 = (const float*)d_in[14];
  const float* b_om1 = (const float*)d_in[15];
  const float* w_om2 = (const float*)d_in[16];
  const float* b_om2 = (const float*)d_in[17];
  const float* w_pe1 = (const float*)d_in[18];
  const float* b_pe1 = (const float*)d_in[19];
  const float* w_pe2 = (const float*)d_in[20];
  const float* b_pe2 = (const float*)d_in[21];

  const int B = in_sizes[0] / 512;
  const long nsteps = ((long)out_size - (long)B * 640) / ((long)B * 513);
  short* wsb = (short*)d_ws;
  float* out = (float*)d_out;

  auto prep = [&](const float* A, const float* Bp, long off, int N, int K, int ks) {
    const int total = N * K;
    prep_frag<<<dim3((total + 255) / 256), dim3(256), 0, stream>>>(A, Bp, wsb + off, N, K, ks);
  };
  prep(w_se1, w_se1, OFF_SE1, 256, 512, 512);
  prep(w_se2, w_se2, OFF_SE2, 128, 256, 256);
  prep(w_ih0, w_hh0, OFF_W0, 1024, 384, 128);
  prep(w_ih1, w_hh1, OFF_W1, 1024, 512, 256);
  prep(w_om1, w_om1, OFF_OM1, 256, 384, 384);
  prep(w_om2, w_om2, OFF_OM2, 512, 256, 256);
  prep(w_pe1, w_pe1, OFF_PE1, 128, 512, 512);

  float* probs = out + (size_t)B * nsteps * 512;
  float* outS  = out + (size_t)B * nsteps * 513;
  float* outF  = outS + (size_t)B * 128;
  atg_main<<<dim3(B / 32), dim3(512), 0, stream>>>(base, cf, b_se1, b_se2, b_ih0, b_hh0,
      b_ih1, b_hh1, b_om1, b_om2, b_pe1, w_pe2, b_pe2, wsb, out, probs, outS, outF, (int)nsteps);
}

// Round 4
// 3105.117 us; speedup vs baseline: 1.3943x; 1.3943x over previous
//
#include <hip/hip_runtime.h>

typedef short bf16x8 __attribute__((ext_vector_type(8)));
typedef float f32x4 __attribute__((ext_vector_type(4)));

#define DEV __device__ __forceinline__

DEV short f2bf(float f) {
  union { float f; unsigned u; } v; v.f = f;
  unsigned r = v.u + 0x7FFFu + ((v.u >> 16) & 1u);
  return (short)(r >> 16);
}
DEV float bf2f(short s) {
  union { unsigned u; float f; } v; v.u = ((unsigned)(unsigned short)s) << 16;
  return v.f;
}
DEV float sigm(float x) { return 1.0f / (1.0f + __expf(-x)); }
DEV float tanh_(float x) {
  float a = fabsf(x);
  float e = __expf(-2.0f * a);
  float t = (1.0f - e) / (1.0f + e);
  return copysignf(t, x);
}

// ---------------- LDS layout (bytes), 64 batch rows per wg, 16 waves.
// bf16 2D arrays XOR-swizzled: byte ^= (row&7)<<4
#define LDS_S    0        // s : 64 x 128 bf16, stride 256   (16 KB) — persists
#define LDS_H0   16384    // h0: 64 x 256 bf16, stride 512   (32 KB) — persists (also SE1-temp)
#define LDS_H1   49152    // h1: 64 x 256 bf16, stride 512   (32 KB) — persists
#define LDS_SLAB 81920    // 64 KB transient: CF (stride 1024) / U (stride 512) / NX (stride 1024)
#define LDS_PROB 147456   // 8 x 64 f32 (2 KB)
#define LDS_SZ   149504

// ---------------- workspace offsets (shorts)
#define OFF_SE1 0
#define OFF_SE2 131072
#define OFF_W0  163840
#define OFF_W1  557056
#define OFF_OM1 1081344
#define OFF_OM2 1179648
#define OFF_PE1 1310720

// Weight prep: gather into MFMA fragment order.
// element e = ((ntile*KK + kk)*64 + lane)*8 + j <-> W[ntile*16 + (lane&15)][kk*32 + (lane>>4)*8 + j]
__global__ void prep_frag(const float* __restrict__ srcA, const float* __restrict__ srcB,
                          short* __restrict__ dst, int N, int K, int ksplit)
{
  const int e = blockIdx.x * 256 + threadIdx.x;
  if (e >= N * K) return;
  const int f = e >> 9;
  const int rix = e & 511;
  const int lane = rix >> 3, j = rix & 7;
  const int KK = K >> 5;
  const int ntile = f / KK, kk = f - ntile * KK;
  const int n = ntile * 16 + (lane & 15);
  const int k = kk * 32 + ((lane >> 4) << 3) + j;
  float v;
  if (k < ksplit) v = srcA[(size_t)n * ksplit + k];
  else            v = srcB[(size_t)n * (K - ksplit) + (k - ksplit)];
  dst[e] = f2bf(v);
}

template<int NT, int MT>
DEV void zacc(f32x4 (&acc)[NT][MT]) {
  #pragma unroll
  for (int n = 0; n < NT; ++n)
    #pragma unroll
    for (int m = 0; m < MT; ++m)
      acc[n][m] = (f32x4){0.f, 0.f, 0.f, 0.f};
}

// Tile-matmul with 8-deep flat-ring B prefetch (static slots; counted vmcnt).
template<int KK, int NT, int MT>
DEV void mm_tiles(const char* sm, int aBase0, int aStride0, int splitKB,
                  int aBase1, int aStride1,
                  const short* __restrict__ wf, int ntBase, int ntStride,
                  f32x4 (&acc)[NT][MT], int lane)
{
  const int l15 = lane & 15, l4 = lane >> 4;
  const short* wp = wf + lane * 8;
  constexpr int TOT = KK * NT;
  constexpr int D = TOT < 8 ? TOT : 8;
  bf16x8 rb[D];
  #pragma unroll
  for (int f = 0; f < D; ++f) {
    const int kkf = f / NT, ntf = f % NT;
    rb[f] = *(const bf16x8*)(wp + (size_t)((ntBase + ntf * ntStride) * KK + kkf) * 512);
  }
  #pragma unroll
  for (int kk = 0; kk < KK; ++kk) {
    const int kb = kk * 64 + l4 * 16;
    bf16x8 a[MT];
    #pragma unroll
    for (int m = 0; m < MT; ++m) {
      const int r = m * 16 + l15;
      int off;
      if (kb < splitKB) off = aBase0 + r * aStride0 + (kb ^ ((r & 7) << 4));
      else              off = aBase1 + r * aStride1 + ((kb - splitKB) ^ ((r & 7) << 4));
      a[m] = *(const bf16x8*)(sm + off);
    }
    #pragma unroll
    for (int nt = 0; nt < NT; ++nt) {
      const int f = kk * NT + nt;
      const int slot = f % D;
      #pragma unroll
      for (int m = 0; m < MT; ++m)
        acc[nt][m] = __builtin_amdgcn_mfma_f32_16x16x32_bf16(a[m], rb[slot], acc[nt][m], 0, 0, 0);
      if (f + D < TOT) {
        const int f2 = f + D, kk2 = f2 / NT, nt2 = f2 % NT;
        rb[slot] = *(const bf16x8*)(wp + (size_t)((ntBase + nt2 * ntStride) * KK + kk2) * 512);
      }
    }
  }
}

// LSTM elementwise: 16 (m,q) cells per lane; c packed as 2xbf16 per reg.
DEV void lstm_ew(f32x4 (&acc)[4][4], f32x4 bv, unsigned (&cpk)[8], unsigned (&hp)[8])
{
  #pragma unroll
  for (int m = 0; m < 4; ++m)
    #pragma unroll
    for (int qh = 0; qh < 2; ++qh) {
      const int pi = m * 2 + qh;
      const unsigned oldc = cpk[pi];
      unsigned newc = 0, newh = 0;
      #pragma unroll
      for (int ql = 0; ql < 2; ++ql) {
        const int q = qh * 2 + ql;
        const float gi = acc[0][m][q] + bv[0];
        const float gf = acc[1][m][q] + bv[1];
        const float gg = acc[2][m][q] + bv[2];
        const float go = acc[3][m][q] + bv[3];
        const float cold = bf2f((short)((oldc >> (ql * 16)) & 0xFFFFu));
        const float c = sigm(gf) * cold + sigm(gi) * tanh_(gg);
        const float h = sigm(go) * tanh_(c);
        newc |= ((unsigned)(unsigned short)f2bf(c)) << (ql * 16);
        newh |= ((unsigned)(unsigned short)f2bf(h)) << (ql * 16);
      }
      cpk[pi] = newc;
      hp[pi] = newh;
    }
}

// ---------------- main fused kernel: 64 rows/wg, 16 waves, full scan + PE head
__global__ __launch_bounds__(1024, 4) void atg_main(
    const float* __restrict__ base, const float* __restrict__ cf,
    const float* __restrict__ b_se1, const float* __restrict__ b_se2,
    const float* __restrict__ b_ih0, const float* __restrict__ b_hh0,
    const float* __restrict__ b_ih1, const float* __restrict__ b_hh1,
    const float* __restrict__ b_om1, const float* __restrict__ b_om2,
    const float* __restrict__ b_pe1, const float* __restrict__ w_pe2,
    const float* __restrict__ b_pe2,
    const short* __restrict__ wsb,
    float* __restrict__ outStates, float* __restrict__ probs,
    float* __restrict__ outS, float* __restrict__ outFinal, int nsteps)
{
  __shared__ __align__(16) char sm[LDS_SZ];
  const int tid = threadIdx.x;
  const int lane = tid & 63, wid = tid >> 6;     // wid 0..15
  const int l15 = lane & 15, l4 = lane >> 4;
  const int row0 = blockIdx.x * 64;

  // cur in registers: curv[i*16+m*4+q] = cur[m*16+l4*4+q][(wid*2+i)*16+l15]
  float curv[32];
  #pragma unroll
  for (int i = 0; i < 2; ++i)
    #pragma unroll
    for (int m = 0; m < 4; ++m)
      #pragma unroll
      for (int q = 0; q < 4; ++q)
        curv[i * 16 + m * 4 + q] =
            base[(size_t)(row0 + m * 16 + l4 * 4 + q) * 512 + (wid * 2 + i) * 16 + l15];

  // ---- stage counterfactual_scenario -> SLAB (bf16, stride 1024, swizzled)
  {
    const int r = tid >> 4, ci = tid & 15;
    const float* src = cf + (size_t)(row0 + r) * 512;
    #pragma unroll
    for (int i = 0; i < 8; ++i) {
      const int c = ci * 4 + i * 64;
      const float4 v = *(const float4*)(src + c);
      short4 h; h.x = f2bf(v.x); h.y = f2bf(v.y); h.z = f2bf(v.z); h.w = f2bf(v.w);
      *(short4*)(sm + LDS_SLAB + r * 1024 + ((c * 2) ^ ((r & 7) << 4))) = h;
    }
  }
  __syncthreads();

  // ---- SE1: relu(cf @ Wse1^T + b) -> temp U in H0 region (stride 512). 16 waves, NT=1.
  {
    f32x4 acc[1][4]; zacc(acc);
    mm_tiles<16, 1, 4>(sm, LDS_SLAB, 1024, 1 << 28, LDS_SLAB, 1024, wsb + OFF_SE1, wid, 1, acc, lane);
    const int cc = wid * 16 + l15;
    const float bv = b_se1[cc];
    #pragma unroll
    for (int m = 0; m < 4; ++m)
      #pragma unroll
      for (int q = 0; q < 4; ++q) {
        const int rr = m * 16 + l4 * 4 + q;
        const float u = fmaxf(acc[0][m][q] + bv, 0.0f);
        *(short*)(sm + LDS_H0 + rr * 512 + ((cc * 2) ^ ((rr & 7) << 4))) = f2bf(u);
      }
  }
  __syncthreads();

  // ---- SE2: s = u @ Wse2^T + b -> S (stride 256) + outS. waves 0-7.
  if (wid < 8) {
    f32x4 acc[1][4]; zacc(acc);
    mm_tiles<8, 1, 4>(sm, LDS_H0, 512, 1 << 28, LDS_H0, 512, wsb + OFF_SE2, wid, 1, acc, lane);
    const int cc = wid * 16 + l15;
    const float bv = b_se2[cc];
    #pragma unroll
    for (int m = 0; m < 4; ++m)
      #pragma unroll
      for (int q = 0; q < 4; ++q) {
        const int rr = m * 16 + l4 * 4 + q;
        const float v = acc[0][m][q] + bv;
        __builtin_nontemporal_store(v, outS + (size_t)(row0 + rr) * 128 + cc);
        *(short*)(sm + LDS_S + rr * 256 + ((cc * 2) ^ ((rr & 7) << 4))) = f2bf(v);
      }
  }
  __syncthreads();
  // ---- zero h0/h1 (64 KB contiguous)
  #pragma unroll
  for (int i = 0; i < 4; ++i)
    *(f32x4*)(sm + LDS_H0 + tid * 64 + i * 16) = (f32x4){0.f, 0.f, 0.f, 0.f};
  __syncthreads();

  // ---- persistent biases
  f32x4 b0v, b1v;
  #pragma unroll
  for (int g = 0; g < 4; ++g) {
    const int c = g * 256 + wid * 16 + l15;
    b0v[g] = b_ih0[c] + b_hh0[c];
    b1v[g] = b_ih1[c] + b_hh1[c];
  }
  const float bo1 = b_om1[wid * 16 + l15];
  float bo2[2];
  #pragma unroll
  for (int i = 0; i < 2; ++i) bo2[i] = b_om2[(wid * 2 + i) * 16 + l15];
  float bp1 = 0.f, w2v = 0.f;
  if (wid < 8) { bp1 = b_pe1[wid * 16 + l15]; w2v = w_pe2[wid * 16 + l15]; }

  unsigned c0[8], c1[8];
  #pragma unroll
  for (int i = 0; i < 8; ++i) { c0[i] = 0u; c1[i] = 0u; }

  for (int step = 0; step < nsteps; ++step) {
    unsigned hp[8];
    // ===== phase A: LSTM layer 0, A = [s | h0], K=384, NT=4 gate-local
    {
      f32x4 acc[4][4]; zacc(acc);
      mm_tiles<12, 4, 4>(sm, LDS_S, 256, 256, LDS_H0, 512, wsb + OFF_W0, wid, 16, acc, lane);
      lstm_ew(acc, b0v, c0, hp);
    }
    __syncthreads();                               // (1) old-h0 reads done
    #pragma unroll
    for (int m = 0; m < 4; ++m)
      #pragma unroll
      for (int q = 0; q < 4; ++q) {
        const int rr = m * 16 + l4 * 4 + q;
        const int cc = wid * 16 + l15;
        const unsigned v = hp[m * 2 + (q >> 1)] >> ((q & 1) * 16);
        *(short*)(sm + LDS_H0 + rr * 512 + ((cc * 2) ^ ((rr & 7) << 4))) = (short)v;
      }
    __syncthreads();                               // (2)
    // ===== phase B: LSTM layer 1, A = [h0 | h1], K=512
    {
      f32x4 acc[4][4]; zacc(acc);
      mm_tiles<16, 4, 4>(sm, LDS_H0, 512, 512, LDS_H1, 512, wsb + OFF_W1, wid, 16, acc, lane);
      lstm_ew(acc, b1v, c1, hp);
    }
    __syncthreads();                               // (3) old-h1 reads done
    #pragma unroll
    for (int m = 0; m < 4; ++m)
      #pragma unroll
      for (int q = 0; q < 4; ++q) {
        const int rr = m * 16 + l4 * 4 + q;
        const int cc = wid * 16 + l15;
        const unsigned v = hp[m * 2 + (q >> 1)] >> ((q & 1) * 16);
        *(short*)(sm + LDS_H1 + rr * 512 + ((cc * 2) ^ ((rr & 7) << 4))) = (short)v;
      }
    __syncthreads();                               // (4)
    // ===== phase C: u = relu([h1|s] @ Wom1^T + b) -> U in SLAB (stride 512)
    {
      f32x4 acc[1][4]; zacc(acc);
      mm_tiles<12, 1, 4>(sm, LDS_H1, 512, 512, LDS_S, 256, wsb + OFF_OM1, wid, 1, acc, lane);
      const int cc = wid * 16 + l15;
      #pragma unroll
      for (int m = 0; m < 4; ++m)
        #pragma unroll
        for (int q = 0; q < 4; ++q) {
          const int rr = m * 16 + l4 * 4 + q;
          const float u = fmaxf(acc[0][m][q] + bo1, 0.0f);
          *(short*)(sm + LDS_SLAB + rr * 512 + ((cc * 2) ^ ((rr & 7) << 4))) = f2bf(u);
        }
    }
    __syncthreads();                               // (5)
    // ===== phase D: nxt = cur + 0.1*tanh(u @ Wom2^T + b); cur in regs; NT stores
    {
      f32x4 acc[2][4]; zacc(acc);
      mm_tiles<8, 2, 4>(sm, LDS_SLAB, 512, 1 << 28, LDS_SLAB, 512, wsb + OFF_OM2, wid * 2, 1, acc, lane);
      #pragma unroll
      for (int i = 0; i < 2; ++i) {
        const int cc = (wid * 2 + i) * 16 + l15;
        #pragma unroll
        for (int m = 0; m < 4; ++m)
          #pragma unroll
          for (int q = 0; q < 4; ++q) {
            const int rr = m * 16 + l4 * 4 + q;
            const int ci = i * 16 + m * 4 + q;
            const float nx = curv[ci] + 0.1f * tanh_(acc[i][m][q] + bo2[i]);
            curv[ci] = nx;
            __builtin_nontemporal_store(nx,
                outStates + ((size_t)(row0 + rr) * nsteps + step) * 512 + cc);
          }
      }
    }
    __syncthreads();                               // (6) all U reads done
    // ---- stage nx -> SLAB (stride 1024) for PE
    #pragma unroll
    for (int i = 0; i < 2; ++i)
      #pragma unroll
      for (int m = 0; m < 4; ++m)
        #pragma unroll
        for (int q = 0; q < 4; ++q) {
          const int rr = m * 16 + l4 * 4 + q;
          const int cc = (wid * 2 + i) * 16 + l15;
          *(short*)(sm + LDS_SLAB + rr * 1024 + ((cc * 2) ^ ((rr & 7) << 4))) =
              f2bf(curv[i * 16 + m * 4 + q]);
        }
    __syncthreads();                               // (7)
    // ===== phase PE: prob = sigmoid(relu(nx @ Wpe1^T + b) @ w_pe2 + b). waves 0-7.
    if (wid < 8) {
      f32x4 acc[1][4]; zacc(acc);
      mm_tiles<16, 1, 4>(sm, LDS_SLAB, 1024, 1 << 28, LDS_SLAB, 1024, wsb + OFF_PE1, wid, 1, acc, lane);
      float part[16];
      #pragma unroll
      for (int m = 0; m < 4; ++m)
        #pragma unroll
        for (int q = 0; q < 4; ++q)
          part[m * 4 + q] = fmaxf(acc[0][m][q] + bp1, 0.0f) * w2v;
      #pragma unroll
      for (int d = 1; d < 16; d <<= 1)
        #pragma unroll
        for (int i = 0; i < 16; ++i)
          part[i] += __shfl_xor(part[i], d);
      if (l15 == 0) {
        #pragma unroll
        for (int m = 0; m < 4; ++m)
          #pragma unroll
          for (int q = 0; q < 4; ++q)
            *(float*)(sm + LDS_PROB + (wid * 64 + m * 16 + l4 * 4 + q) * 4) = part[m * 4 + q];
      }
    }
    __syncthreads();                               // (8)
    if (tid < 64) {
      float ssum = b_pe2[0];
      #pragma unroll
      for (int w = 0; w < 8; ++w)
        ssum += *(const float*)(sm + LDS_PROB + (w * 64 + tid) * 4);
      const float p = 1.0f / (1.0f + __expf(-ssum));
      __builtin_nontemporal_store(p, probs + (size_t)(row0 + tid) * nsteps + step);
    }
    // next write to PROB/SLAB is ≥2 barriers away -> safe
  }

  // ---- final timeline state from registers
  #pragma unroll
  for (int i = 0; i < 2; ++i)
    #pragma unroll
    for (int m = 0; m < 4; ++m)
      #pragma unroll
      for (int q = 0; q < 4; ++q)
        __builtin_nontemporal_store(curv[i * 16 + m * 4 + q],
            outFinal + (size_t)(row0 + m * 16 + l4 * 4 + q) * 512 + (wid * 2 + i) * 16 + l15);
}

extern "C" void kernel_launch(void* const* d_in, const int* in_sizes, int n_in,
                              void* d_out, int out_size, void* d_ws, size_t ws_size,
                              hipStream_t stream)
{
  const float* base  = (const float*)d_in[0];
  const float* cf    = (const float*)d_in[1];
  const float* w_se1 = (const float*)d_in[2];
  const float* b_se1 = (const float*)d_in[3];
  const float* w_se2 = (const float*)d_in[4];
  const float* b_se2 = (const float*)d_in[5];
  const float* w_ih0 = (const float*)d_in[6];
  const float* w_hh0 = (const float*)d_in[7];
  const float* b_ih0 = (const float*)d_in[8];
  const float* b_hh0 = (const float*)d_in[9];
  const float* w_ih1 = (const float*)d_in[10];
  const float* w_hh1 = (const float*)d_in[11];
  const float* b_ih1 = (const float*)d_in[12];
  const float* b_hh1 = (const float*)d_in[13];
  const float* w_om1 = (const float*)d_in[14];
  const float* b_om1 = (const float*)d_in[15];
  const float* w_om2 = (const float*)d_in[16];
  const float* b_om2 = (const float*)d_in[17];
  const float* w_pe1 = (const float*)d_in[18];
  const float* b_pe1 = (const float*)d_in[19];
  const float* w_pe2 = (const float*)d_in[20];
  const float* b_pe2 = (const float*)d_in[21];

  const int B = in_sizes[0] / 512;
  const long nsteps = ((long)out_size - (long)B * 640) / ((long)B * 513);
  short* wsb = (short*)d_ws;
  float* out = (float*)d_out;

  auto prep = [&](const float* A, const float* Bp, long off, int N, int K, int ks) {
    const int total = N * K;
    prep_frag<<<dim3((total + 255) / 256), dim3(256), 0, stream>>>(A, Bp, wsb + off, N, K, ks);
  };
  prep(w_se1, w_se1, OFF_SE1, 256, 512, 512);
  prep(w_se2, w_se2, OFF_SE2, 128, 256, 256);
  prep(w_ih0, w_hh0, OFF_W0, 1024, 384, 128);
  prep(w_ih1, w_hh1, OFF_W1, 1024, 512, 256);
  prep(w_om1, w_om1, OFF_OM1, 256, 384, 384);
  prep(w_om2, w_om2, OFF_OM2, 512, 256, 256);
  prep(w_pe1, w_pe1, OFF_PE1, 128, 512, 512);

  float* probs = out + (size_t)B * nsteps * 512;
  float* outS  = out + (size_t)B * nsteps * 513;
  float* outF  = outS + (size_t)B * 128;
  atg_main<<<dim3(B / 64), dim3(1024), 0, stream>>>(base, cf, b_se1, b_se2, b_ih0, b_hh0,
      b_ih1, b_hh1, b_om1, b_om2, b_pe1, w_pe2, b_pe2, wsb, out, probs, outS, outF, (int)nsteps);
}